// Round 8
// baseline (130.965 us; speedup 1.0000x reference)
//
#include <hip/hip_runtime.h>

#define EPSN 1e-12f

// ---- problem constants ----
#define NB   4
#define CC   128
#define KK_  64
#define HH   40
#define WW   40
#define HWP  1600      // H*W
#define HO   18
#define WO   18
#define HWO  324       // HO*WO
#define KCC  8192      // K*C

// ws layout (floats)
#define WS_T   0                      // 4*324*8192 = 10,616,832
#define WS_XN  10616832               // 4*1600*128 = 819200
#define WS_A   11436032               // 4*1600*64  = 409600
#define WS_GP  11845632               // 64*8192    = 524288
#define WS_G0  12369920               // 64*64      = 4096

// k1 xs swizzle: XOR c-bits[2:6] with px (involution).
static __device__ __forceinline__ int swzk1(int c, int px){ return c ^ ((px & 31) << 2); }

// async global->LDS staging, 16B per lane: dest = ldsbase + lane*16.
__device__ __forceinline__ void gl_lds16(const float* g, float* l)
{
  __builtin_amdgcn_global_load_lds(
      (const __attribute__((address_space(1))) void*)g,
      (__attribute__((address_space(3))) void*)l, 16, 0, 0);
}

// =====================================================================
// Kernel 1: per-pixel L2 norm -> xn (pix-major), conv dots + softmax -> a
// (unchanged from R7)
// =====================================================================
__global__ __launch_bounds__(1024) void k1_norm_assign(
    const float* __restrict__ x, const float* __restrict__ w,
    float* __restrict__ xn, float* __restrict__ aout)
{
  __shared__ __align__(16) float xs[64][128];
  __shared__ float ds[64][65];
  __shared__ float invs[64];
  const int t = threadIdx.x;
  const int b = blockIdx.x;          // 0..99
  const int n = b / 25;
  const int pixb = (b % 25) * 64;
  const float* xb = x + (size_t)n * CC * HWP + pixb;

  {
    const int px = t & 63, cs = t >> 6;
    #pragma unroll
    for (int j = 0; j < 8; ++j) {
      const int c = cs + 16 * j;
      xs[px][swzk1(c, px)] = xb[c * HWP + px];
    }
  }
  __syncthreads();
  {
    const int p = t >> 4, q = t & 15;
    float ss = 0.f;
    #pragma unroll
    for (int j = 0; j < 8; ++j) {
      const float v = xs[p][swzk1(q + 16 * j, p)];
      ss += v * v;
    }
    ss += __shfl_xor(ss, 1); ss += __shfl_xor(ss, 2);
    ss += __shfl_xor(ss, 4); ss += __shfl_xor(ss, 8);
    if (q == 0) invs[p] = 1.f / fmaxf(sqrtf(ss), EPSN);
  }
  __syncthreads();
  {
    float* xno = xn + ((size_t)n * HWP + pixb) * CC;
    #pragma unroll
    for (int rr = 0; rr < 8; ++rr) {
      const int i = t + rr * 1024;
      const int pp = i >> 7, c = i & 127;
      const float v = xs[pp][swzk1(c, pp)] * invs[pp];
      xs[pp][swzk1(c, pp)] = v;
      xno[i] = v;
    }
  }
  __syncthreads();
  {
    const int lane = t & 63;
    const int wv = __builtin_amdgcn_readfirstlane(t >> 6);
    float acc[4] = {0.f, 0.f, 0.f, 0.f};
    #pragma unroll 4
    for (int c4 = 0; c4 < 32; ++c4) {
      const float4 x4 = *(const float4*)&xs[lane][(c4 << 2) ^ ((lane & 31) << 2)];
      #pragma unroll
      for (int kk = 0; kk < 4; ++kk) {
        const float* wr = &w[(wv * 4 + kk) * CC + (c4 << 2)];
        acc[kk] += x4.x * wr[0] + x4.y * wr[1] + x4.z * wr[2] + x4.w * wr[3];
      }
    }
    #pragma unroll
    for (int kk = 0; kk < 4; ++kk) ds[lane][wv * 4 + kk] = acc[kk];
  }
  __syncthreads();
  {
    const int p = t >> 4, q = t & 15;
    float v[4]; float m = -3.4e38f;
    #pragma unroll
    for (int kk = 0; kk < 4; ++kk){ v[kk] = ds[p][q + 16 * kk]; m = fmaxf(m, v[kk]); }
    m = fmaxf(m, __shfl_xor(m, 1)); m = fmaxf(m, __shfl_xor(m, 2));
    m = fmaxf(m, __shfl_xor(m, 4)); m = fmaxf(m, __shfl_xor(m, 8));
    float s = 0.f;
    #pragma unroll
    for (int kk = 0; kk < 4; ++kk){ v[kk] = __expf(v[kk] - m); s += v[kk]; }
    s += __shfl_xor(s, 1); s += __shfl_xor(s, 2);
    s += __shfl_xor(s, 4); s += __shfl_xor(s, 8);
    const float is = 1.f / s;
    #pragma unroll
    for (int kk = 0; kk < 4; ++kk) ds[p][q + 16 * kk] = v[kk] * is;
  }
  __syncthreads();
  {
    float* ao = aout + ((size_t)n * HWP + pixb) * KK_;
    #pragma unroll
    for (int rr = 0; rr < 4; ++rr) {
      const int i = t + rr * 1024;
      ao[i] = ds[i >> 6][i & 63];
    }
  }
}

// =====================================================================
// Kernel 2: DUAL-WINDOW regional blocks. Block = (n, ho, wo-pair): windows
// wo0, wo0+1 share a 5x7 pixel tile (35 pixels staged once). Per lane:
// 70 b128 LDS reads feed 50 FMA-sets (vs 100 reads in two single-window
// blocks) -> -30% on the shared LDS pipe. 648 + 64 full-path blocks.
// 512 threads (8 waves); lane owns k0..k0+3 (k0 = wv*8+4h), c0..c0+3.
// LDS flat, staged by full-1KB global_load_lds calls; over-reads land in
// adjacent ws regions (safe, never consumed).
// =====================================================================
__global__ __launch_bounds__(512, 4) void k2_main(
    const float* __restrict__ xn, const float* __restrict__ aw,
    const float* __restrict__ cent, float* __restrict__ T,
    float* __restrict__ Gpart, float* __restrict__ G0part)
{
  __shared__ __align__(16) float a_s[2560];   // regional: [5 dy][512], full: flat 1792
  __shared__ __align__(16) float xs[5120];    // regional: [5 dy][1024], full: flat 3328
  __shared__ float red[16];
  const int t = threadIdx.x;
  const int lane = t & 63;
  const int wv = t >> 6;            // 0..7
  const int h = lane >> 5;
  const int c0 = (lane & 31) << 2;
  const int k0 = wv * 8 + h * 4;
  // XCD-chunked bijective swizzle (712 = 8*89)
  const int bid = (blockIdx.x & 7) * 89 + (blockIdx.x >> 3);

  float accA[16], accB[16];
  #pragma unroll
  for (int j = 0; j < 16; ++j) { accA[j] = 0.f; accB[j] = 0.f; }
  float s0A[4] = {0,0,0,0}, s0B[4] = {0,0,0,0};

  if (bid < 648) {
    // ---------------- regional window pair ----------------
    const int n = bid / 162, rem = bid % 162;
    const int ho = rem / 9, pr = rem % 9;
    const int base = n * HWP + 2 * ho * WW + 4 * pr;   // pixel (2ho, 2*wo0)
    // 30 staging calls (10 a: dy*2+cc; 20 x: dy*4+cc), distributed by wave
    #pragma unroll
    for (int i = 0; i < 4; ++i) {
      const int id = wv + 8 * i;
      if (id < 10) {
        const int dy = id >> 1, cc = id & 1;
        gl_lds16(aw + (size_t)(base + dy * WW) * KK_ + cc * 256 + ((lane) << 2),
                 &a_s[dy * 512 + cc * 256]);
      } else if (id < 30) {
        const int rel = id - 10, dy = rel >> 2, cc = rel & 3;
        gl_lds16(xn + (size_t)(base + dy * WW) * CC + cc * 256 + ((lane) << 2),
                 &xs[dy * 1024 + cc * 256]);
      }
    }
    __syncthreads();

    // dual-window rank-25: col j feeds w0 (j<5) and/or w1 (j>=2)
    for (int dy = 0; dy < 5; ++dy) {
      #pragma unroll
      for (int j = 0; j < 7; ++j) {
        const float4 a4 = *(const float4*)&a_s[dy * 512 + j * 64 + k0];
        const float4 x4 = *(const float4*)&xs[dy * 1024 + j * 128 + c0];
        const float av[4] = {a4.x, a4.y, a4.z, a4.w};
        if (j < 5) {
          #pragma unroll
          for (int m = 0; m < 4; ++m) {
            s0A[m] += av[m];
            accA[m*4+0] += av[m]*x4.x; accA[m*4+1] += av[m]*x4.y;
            accA[m*4+2] += av[m]*x4.z; accA[m*4+3] += av[m]*x4.w;
          }
        }
        if (j >= 2) {
          #pragma unroll
          for (int m = 0; m < 4; ++m) {
            s0B[m] += av[m];
            accB[m*4+0] += av[m]*x4.x; accB[m*4+1] += av[m]*x4.y;
            accB[m*4+2] += av[m]*x4.z; accB[m*4+3] += av[m]*x4.w;
          }
        }
      }
    }

    // epilogue both windows: centroid correction, /25, intra+global norms
    float ssmA[4], ssmB[4], rnmA[4], rnmB[4];
    #pragma unroll
    for (int m = 0; m < 4; ++m) {
      const float4 c4 = *(const float4*)&cent[(size_t)(k0 + m) * CC + c0];
      const float cv[4] = {c4.x, c4.y, c4.z, c4.w};
      float sa = 0.f, sb = 0.f;
      #pragma unroll
      for (int d = 0; d < 4; ++d) {
        const float pa = (accA[m*4+d] - cv[d] * s0A[m]) * 0.04f;
        const float pb = (accB[m*4+d] - cv[d] * s0B[m]) * 0.04f;
        accA[m*4+d] = pa; accB[m*4+d] = pb;
        sa += pa * pa; sb += pb * pb;
      }
      ssmA[m] = sa; ssmB[m] = sb;
    }
    #pragma unroll
    for (int off = 1; off <= 16; off <<= 1) {
      #pragma unroll
      for (int m = 0; m < 4; ++m) {
        ssmA[m] += __shfl_xor(ssmA[m], off);
        ssmB[m] += __shfl_xor(ssmB[m], off);
      }
    }
    float gplA = 0.f, gplB = 0.f;
    #pragma unroll
    for (int m = 0; m < 4; ++m) {
      rnmA[m] = 1.f / fmaxf(sqrtf(ssmA[m]), EPSN);
      rnmB[m] = 1.f / fmaxf(sqrtf(ssmB[m]), EPSN);
      gplA += ssmA[m] * rnmA[m] * rnmA[m];
      gplB += ssmB[m] * rnmB[m] * rnmB[m];
    }
    gplA += __shfl_xor(gplA, 32);
    gplB += __shfl_xor(gplB, 32);
    if (lane == 0) { red[wv] = gplA; red[8 + wv] = gplB; }
    __syncthreads();
    float gtA = 0.f, gtB = 0.f;
    #pragma unroll
    for (int i = 0; i < 8; ++i) { gtA += red[i]; gtB += red[8 + i]; }
    const float giA = 1.f / fmaxf(sqrtf(gtA), EPSN);
    const float giB = 1.f / fmaxf(sqrtf(gtB), EPSN);

    const int r0 = ho * 18 + 2 * pr;
    float* tbA = T + ((size_t)n * HWO + r0) * KCC;
    float* tbB = tbA + KCC;
    #pragma unroll
    for (int m = 0; m < 4; ++m) {
      const float sa = rnmA[m] * giA, sb = rnmB[m] * giB;
      float4 va, vb;
      va.x = accA[m*4+0]*sa; va.y = accA[m*4+1]*sa;
      va.z = accA[m*4+2]*sa; va.w = accA[m*4+3]*sa;
      vb.x = accB[m*4+0]*sb; vb.y = accB[m*4+1]*sb;
      vb.z = accB[m*4+2]*sb; vb.w = accB[m*4+3]*sb;
      *(float4*)&tbA[(size_t)(k0 + m) * CC + c0] = va;
      *(float4*)&tbB[(size_t)(k0 + m) * CC + c0] = vb;
    }
  } else {
    // ---------------- vlad_full partials: 100-pixel chunk, 4 rounds ------
    const int pid = bid - 648;             // 0..63
    const int n = pid >> 4, ch = pid & 15;
    #pragma unroll 1
    for (int rr = 0; rr < 4; ++rr) {
      const int pb = n * HWP + ch * 100 + rr * 25;
      // 20 calls: 7 a (1792 fl >= 1600) + 13 x (3328 fl >= 3200)
      #pragma unroll
      for (int i = 0; i < 3; ++i) {
        const int id = wv + 8 * i;
        if (id < 7) {
          gl_lds16(aw + (size_t)pb * KK_ + id * 256 + (lane << 2),
                   &a_s[id * 256]);
        } else if (id < 20) {
          const int rel = id - 7;
          gl_lds16(xn + (size_t)pb * CC + rel * 256 + (lane << 2),
                   &xs[rel * 256]);
        }
      }
      __syncthreads();
      #pragma unroll 5
      for (int p = 0; p < 25; ++p) {
        const float4 a4 = *(const float4*)&a_s[p * 64 + k0];
        const float4 x4 = *(const float4*)&xs[p * 128 + c0];
        const float av[4] = {a4.x, a4.y, a4.z, a4.w};
        #pragma unroll
        for (int m = 0; m < 4; ++m) {
          s0A[m] += av[m];
          accA[m*4+0] += av[m]*x4.x; accA[m*4+1] += av[m]*x4.y;
          accA[m*4+2] += av[m]*x4.z; accA[m*4+3] += av[m]*x4.w;
        }
      }
      __syncthreads();
    }
    if ((lane & 31) == 0) {
      #pragma unroll
      for (int m = 0; m < 4; ++m)
        G0part[(size_t)pid * KK_ + k0 + m] = s0A[m];
    }
    float* gb = Gpart + (size_t)pid * KCC;
    #pragma unroll
    for (int m = 0; m < 4; ++m) {
      float4 v;
      v.x = accA[m*4+0]; v.y = accA[m*4+1];
      v.z = accA[m*4+2]; v.w = accA[m*4+3];
      *(float4*)&gb[(size_t)(k0 + m) * CC + c0] = v;
    }
  }
}

// =====================================================================
// Kernel 4+3 merged: blocks 0..1535 transpose T -> out; blocks 1536..1539
// finalize vlad_full (256 threads: k = t>>2, 32 c's each).
// =====================================================================
__global__ __launch_bounds__(256) void k4_trans_full(
    const float* __restrict__ T, float* __restrict__ out,
    const float* __restrict__ Gpart, const float* __restrict__ G0part,
    const float* __restrict__ cent, float* __restrict__ outF)
{
  __shared__ float tile[112][65];
  __shared__ float red[4];
  const int t = threadIdx.x;
  const int b = blockIdx.x;

  if (b < 1536) {
    const int n = b / 384;
    const int rem = b % 384;
    const int kcT = rem / 3, rT = rem % 3;
    const int kc0 = kcT * 64;
    const int r0 = rT * 112;
    const int rows = (rT == 2) ? 100 : 112;
    const int w = t >> 6, lane = t & 63;

    for (int rr = w; rr < rows; rr += 4)
      tile[rr][lane] = T[((size_t)n * HWO + r0 + rr) * KCC + kc0 + lane];
    __syncthreads();

    #pragma unroll
    for (int j = 0; j < 16; ++j) {
      const int kcl = w + 4 * j;
      float* orow = out + (size_t)n * KCC * HWO + (size_t)(kc0 + kcl) * HWO + r0;
      orow[lane] = tile[lane][kcl];
      if (lane + 64 < rows) orow[64 + lane] = tile[64 + lane][kcl];
    }
  } else {
    // ---- vlad_full finalize ----
    const int n = b - 1536;
    const int k = t >> 2, cg4 = t & 3;
    const int c0 = cg4 * 32;

    float acc[32];
    #pragma unroll
    for (int j = 0; j < 32; ++j) acc[j] = 0.f;
    float g0 = 0.f;
    #pragma unroll 1
    for (int ch = 0; ch < 16; ++ch) {
      const float* gp = Gpart + ((size_t)(n * 16 + ch)) * KCC + (size_t)k * CC + c0;
      #pragma unroll
      for (int j4 = 0; j4 < 8; ++j4) {
        const float4 g4 = *(const float4*)(gp + (j4 << 2));
        acc[j4*4+0] += g4.x; acc[j4*4+1] += g4.y;
        acc[j4*4+2] += g4.z; acc[j4*4+3] += g4.w;
      }
      g0 += G0part[(size_t)(n * 16 + ch) * KK_ + k];
    }

    float ss = 0.f;
    #pragma unroll
    for (int j = 0; j < 32; ++j) {
      const float v = acc[j] - cent[(size_t)k * CC + c0 + j] * g0;
      acc[j] = v;
      ss += v * v;
    }
    ss += __shfl_xor(ss, 1); ss += __shfl_xor(ss, 2);   // over cg4 -> per-k
    const float rn = 1.f / fmaxf(sqrtf(ss), EPSN);
    float part = (cg4 == 0) ? ss * rn * rn : 0.f;
    #pragma unroll
    for (int o = 1; o < 64; o <<= 1) part += __shfl_xor(part, o);
    if ((t & 63) == 0) red[t >> 6] = part;
    __syncthreads();
    const float tot = red[0] + red[1] + red[2] + red[3];
    const float scale = rn * (1.f / fmaxf(sqrtf(tot), EPSN));
    #pragma unroll
    for (int j4 = 0; j4 < 8; ++j4) {
      float4 v;
      v.x = acc[j4*4+0]*scale; v.y = acc[j4*4+1]*scale;
      v.z = acc[j4*4+2]*scale; v.w = acc[j4*4+3]*scale;
      *(float4*)&outF[(size_t)n * KCC + (size_t)k * CC + c0 + (j4 << 2)] = v;
    }
  }
}

// =====================================================================
extern "C" void kernel_launch(void* const* d_in, const int* in_sizes, int n_in,
                              void* d_out, int out_size, void* d_ws, size_t ws_size,
                              hipStream_t stream)
{
  const float* x    = (const float*)d_in[0];
  const float* w    = (const float*)d_in[1];
  const float* cent = (const float*)d_in[2];
  float* out = (float*)d_out;
  float* ws  = (float*)d_ws;

  float* T  = ws + WS_T;
  float* xn = ws + WS_XN;
  float* aw = ws + WS_A;
  float* gp = ws + WS_GP;
  float* g0 = ws + WS_G0;

  k1_norm_assign<<<dim3(100), dim3(1024), 0, stream>>>(x, w, xn, aw);
  k2_main<<<dim3(712), dim3(512), 0, stream>>>(xn, aw, cent, T, gp, g0);
  k4_trans_full<<<dim3(1540), dim3(256), 0, stream>>>(T, out, gp, g0, cent,
                                                      out + (size_t)NB * KCC * HWO);
}